// Round 6
// baseline (124.825 us; speedup 1.0000x reference)
//
#include <hip/hip_runtime.h>
#include <math.h>

// RandomLowRes2D: per-image Gaussian blur (R=15, symmetric pad) + linear
// down/up resample along a per-image runtime axis.
//
// Fusion: low[j] = (1-fr)*s[la] + fr*s[la+1] collapses blur+downsample into a
// single fused filter on img: cw[k] = fmaf(fr, dwe[k], we[k+1]),
// with dwe[k] = we[k] - we[k+1] precomputed.
//
// Round 10 (ax1 LDS transpose — the LDS pipe is the serialization resource):
//  - ax1 tile stored transposed s_imgT[512][4]: the 4 row values a tap needs
//    are contiguous -> 1 ds_read_b128 per tap (was 4 ds_read_b32; rows were
//    520 floats apart, beyond ds_read2 range). Low writes: 1 ds_write_b128.
//    Upsample: 2 ds_read_b128 per column (was 8 ds_read_b32).
//    => ax1 LDS wave-instruction cycles ~2.3x down (~11us -> ~5us of
//    CU-serialized LDS pipe time across resident blocks).
//  - XOR swizzle SW(t)=t^((t>>3)&7) on s_imgT's 16B-block index: gather
//    lane-stride ~res would land one 4-bank group at res=8 (16-way
//    conflict); swizzle spreads strides 1/2/4/8 across all 8 bank groups.
//    Applied at scatter-write and both read paths (bijective, low-3-bits
//    only -> index stays in [0,512)).
//  - ax0 path, grid order unchanged. Numerics identical (same FMA chains,
//    exact IEEE divides) -> absmax unchanged.

#define RR 15
#define TAPS 31
#define SIG_PER_FWHM 0.42466090014400953f  // 1/sqrt(8 ln 2)
#define SW(t) ((t) ^ (((t) >> 3) & 7))

__global__ __launch_bounds__(256) void lowres2d_kernel(
    const float* __restrict__ x,
    const float* __restrict__ resolution,
    const int*   __restrict__ axis,
    const float* __restrict__ gap,
    float* __restrict__ out)
{
    const int tid = threadIdx.x;
    const int n   = blockIdx.y;          // image index
    const int bx  = blockIdx.x;          // 0..127 (image-contiguous dispatch)

    const float res = resolution[n];
    const int   ax  = axis[n];
    const float gp  = gap[n];

    // ax0 images use 64 blocks of 8 rows; rest exit (block-uniform)
    if (ax == 0 && bx >= 64) return;

    const float sig = fmaxf(res * gp * SIG_PER_FWHM, 1e-6f);
    int n_low = (int)floorf(512.0f / res);
    if (n_low < 1) n_low = 1;
    if (n_low > 512) n_low = 512;
    const float nlm1f = (float)(n_low - 1);

    // adaptive radius: normalized weights < 1e-6 outside +-kr (sum >= 1)
    int kr = (int)(sig * 5.2565f) + 1;
    if (kr > RR) kr = RR;
    const int k0 = RR - kr, k1 = RR + 1 + kr;   // fused window k in [k0, k1]
    const int la_lo = kr, la_hi = 510 - kr;     // interior: no reflect needed

    // wd[k] = { we[k+1], dwe[k] }, k = 0..31; we[0]=we[32]=0 implicit
    __shared__ float2 wd[32];
    // overlaid scratch:
    //   ax1: s_imgT[512][4] (2048) + s_lowT[512][4] (2048) = 4096 floats
    //   ax0: s_lowB[9][512] = 4608 floats
    __shared__ __align__(16) float smem[4608];
    float (*s_imgT)[4]   = (float (*)[4])smem;            // swizzled rows
    float (*s_lowT)[4]   = (float (*)[4])(smem + 2048);   // linear rows
    float (*s_lowB)[512] = (float (*)[512])smem;

    if (tid < 32) {
        const int k = tid;
        float r = 0.0f;
        if (k < TAPS) {
            float d = (float)(k - RR) / sig;
            r = expf(-0.5f * d * d);
        }
        float tot = r;
        tot += __shfl_xor(tot, 1, 32);
        tot += __shfl_xor(tot, 2, 32);
        tot += __shfl_xor(tot, 4, 32);
        tot += __shfl_xor(tot, 8, 32);
        tot += __shfl_xor(tot, 16, 32);
        float rm1 = __shfl_up(r, 1, 32);
        if (k == 0) rm1 = 0.0f;
        const float inv = 1.0f / tot;            // tot >= 1 (center tap)
        wd[k] = make_float2(r * inv, (rm1 - r) * inv);
    }
    __syncthreads();

    const size_t base = (size_t)n * (512 * 512);
    const float* img = x + base;
    float* o = out + base;

    if (ax == 0) {
        // ---- ax0: cooperative low rows, float4/lane, 2 rows per pass ----
        const int i0 = bx * 8;
        const int g  = tid >> 7;                 // group 0/1 (2 waves each)
        const int lt = tid & 127;                // float4 column
        const float4* img4 = (const float4*)img;
        float4* out4 = (float4*)o;

        // needed low rows for output rows [i0, i0+8)
        float pA = fminf((float)i0 / res, nlm1f);
        int jlo = (int)floorf(pA);
        float pB = fminf((float)(i0 + 7) / res, nlm1f);
        int jhi = (int)floorf(pB) + 1;
        if (jhi > n_low - 1) jhi = n_low - 1;
        if (jhi < jlo) jhi = jlo;
        const int nrows = jhi - jlo + 1;         // <= 9 (res >= 1)

        for (int p = 0; p < nrows; p += 2) {     // block-uniform loop
            int rowoff = p + g;                  // group-uniform
            int j = jlo + ((rowoff < nrows) ? rowoff : (nrows - 1));
            float pos = fminf((float)j * res, 511.0f);
            float lof = floorf(pos);
            float fr  = pos - lof;
            int   la  = __builtin_amdgcn_readfirstlane((int)lof);
            float4 acc = make_float4(0.0f, 0.0f, 0.0f, 0.0f);
            if (la >= la_lo && la <= la_hi) {    // wave-uniform branch
                #pragma unroll 4
                for (int k = k0; k <= k1; ++k) {
                    int t = la - RR + k;         // scalar
                    float2 w = wd[k];
                    float cw = fmaf(fr, w.y, w.x);
                    float4 v = img4[(size_t)(t * 128 + lt)];
                    acc.x = fmaf(cw, v.x, acc.x);
                    acc.y = fmaf(cw, v.y, acc.y);
                    acc.z = fmaf(cw, v.z, acc.z);
                    acc.w = fmaf(cw, v.w, acc.w);
                }
            } else {
                for (int k = k0; k <= k1; ++k) {
                    int t = la - RR + k;
                    t = (t < 0)   ? (-1 - t)   : t;  // symmetric reflect
                    t = (t > 511) ? (1023 - t) : t;
                    float2 w = wd[k];
                    float cw = fmaf(fr, w.y, w.x);
                    float4 v = img4[(size_t)(t * 128 + lt)];
                    acc.x = fmaf(cw, v.x, acc.x);
                    acc.y = fmaf(cw, v.y, acc.y);
                    acc.z = fmaf(cw, v.z, acc.z);
                    acc.w = fmaf(cw, v.w, acc.w);
                }
            }
            if (rowoff < nrows) {                // group-uniform guard
                ((float4*)&s_lowB[rowoff][0])[lt] = acc;
            }
        }
        __syncthreads();

        // upsample: 2 output rows per pass, group-uniform position math
        #pragma unroll
        for (int p = 0; p < 4; ++p) {
            int i = i0 + p * 2 + g;              // group-uniform
            float pos2 = fminf((float)i / res, nlm1f);  // exact IEEE div
            float l2f  = floorf(pos2);
            float fr2  = pos2 - l2f;
            int lo2 = (int)l2f;                  // in [jlo, jhi]
            int hi2 = (lo2 + 1 <= jhi) ? (lo2 + 1) : jhi;  // == min(lo2+1, n_low-1)
            float4 A = ((float4*)&s_lowB[lo2 - jlo][0])[lt];
            float4 B = ((float4*)&s_lowB[hi2 - jlo][0])[lt];
            float omf2 = 1.0f - fr2;
            float4 ov;
            ov.x = A.x * omf2 + B.x * fr2;
            ov.y = A.y * omf2 + B.y * fr2;
            ov.z = A.z * omf2 + B.z * fr2;
            ov.w = A.w * omf2 + B.w * fr2;
            out4[(size_t)(i * 128 + lt)] = ov;
        }
    } else {
        // -------- ax1: LDS-tiled 4 rows, transposed + swizzled layout -----
        const int h0 = bx * 4;

        // load 4x512 tile (coalesced float4), scatter transposed into LDS:
        // s_imgT[SW(t)][r] = img[r][t]
        const float4* img4g = (const float4*)(img + (size_t)h0 * 512);
        #pragma unroll
        for (int p = 0; p < 2; ++p) {
            int m = p * 256 + tid;
            int r = m >> 7, c4 = m & 127;
            float4 v = img4g[r * 128 + c4];
            int t0 = c4 * 4;
            s_imgT[SW(t0 + 0)][r] = v.x;
            s_imgT[SW(t0 + 1)][r] = v.y;
            s_imgT[SW(t0 + 2)][r] = v.z;
            s_imgT[SW(t0 + 3)][r] = v.w;
        }
        __syncthreads();

        // low phase: one thread per low column j, all 4 rows via one
        // ds_read_b128 per tap; one ds_write_b128 per column.
        for (int j = tid; j < n_low; j += 256) {
            float pos = fminf((float)j * res, 511.0f);
            float lof = floorf(pos);
            float fr  = pos - lof;
            int   la  = (int)lof;
            float a0 = 0.0f, a1 = 0.0f, a2 = 0.0f, a3 = 0.0f;
            if (la >= la_lo && la <= la_hi) {
                #pragma unroll 4
                for (int k = k0; k <= k1; ++k) {
                    int t = la - RR + k;
                    float2 w = wd[k];
                    float cw = fmaf(fr, w.y, w.x);
                    float4 v = *(const float4*)&s_imgT[SW(t)][0];
                    a0 = fmaf(cw, v.x, a0);
                    a1 = fmaf(cw, v.y, a1);
                    a2 = fmaf(cw, v.z, a2);
                    a3 = fmaf(cw, v.w, a3);
                }
            } else {
                for (int k = k0; k <= k1; ++k) {
                    int t = la - RR + k;
                    t = (t < 0)   ? (-1 - t)   : t;  // symmetric reflect
                    t = (t > 511) ? (1023 - t) : t;
                    float2 w = wd[k];
                    float cw = fmaf(fr, w.y, w.x);
                    float4 v = *(const float4*)&s_imgT[SW(t)][0];
                    a0 = fmaf(cw, v.x, a0);
                    a1 = fmaf(cw, v.y, a1);
                    a2 = fmaf(cw, v.z, a2);
                    a3 = fmaf(cw, v.w, a3);
                }
            }
            float4 acc = make_float4(a0, a1, a2, a3);
            *(float4*)&s_lowT[j][0] = acc;
        }
        __syncthreads();

        // upsample: one thread per column i (2 cols); 2 ds_read_b128 per
        // column serve all 4 rows; coalesced scalar stores.
        #pragma unroll
        for (int p = 0; p < 2; ++p) {
            int i = p * 256 + tid;
            float pos2 = fminf((float)i / res, nlm1f);  // exact IEEE div
            float l2f  = floorf(pos2);
            float fr2  = pos2 - l2f;
            int lo2 = (int)l2f;                  // <= n_low-1 (pos2 clamped)
            int hi2 = (lo2 + 1 < n_low) ? (lo2 + 1) : (n_low - 1);
            float omf2 = 1.0f - fr2;
            float4 A = *(const float4*)&s_lowT[lo2][0];
            float4 B = *(const float4*)&s_lowT[hi2][0];
            o[(size_t)(h0 + 0) * 512 + i] = A.x * omf2 + B.x * fr2;
            o[(size_t)(h0 + 1) * 512 + i] = A.y * omf2 + B.y * fr2;
            o[(size_t)(h0 + 2) * 512 + i] = A.z * omf2 + B.z * fr2;
            o[(size_t)(h0 + 3) * 512 + i] = A.w * omf2 + B.w * fr2;
        }
    }
}

extern "C" void kernel_launch(void* const* d_in, const int* in_sizes, int n_in,
                              void* d_out, int out_size, void* d_ws, size_t ws_size,
                              hipStream_t stream) {
    const float* x          = (const float*)d_in[0];
    const float* resolution = (const float*)d_in[1];
    const int*   axis       = (const int*)d_in[2];
    const float* gap        = (const float*)d_in[3];
    float* out = (float*)d_out;

    const int n_img = in_sizes[1];   // B*C = 64

    dim3 grid(128, n_img);           // bx fastest: per-image sequential streaming
    lowres2d_kernel<<<grid, 256, 0, stream>>>(x, resolution, axis, gap, out);
}